// Round 2
// baseline (13653.320 us; speedup 1.0000x reference)
//
#include <hip/hip_runtime.h>

#define HDIM 512
#define BATCH 16
#define TSTEPS 2048
#define S 8                    // h-elements (j) per workgroup
#define BW 4                   // batches per workgroup
#define NJ (HDIM / S)          // 64 j-groups
#define NG (BATCH / BW)        // 4 batch-groups
#define NWG (NJ * NG)          // 256 workgroups == #CUs
#define NTHR 256

typedef unsigned long long u64;

__device__ __forceinline__ float sigm(float x) { return 1.f / (1.f + __expf(-x)); }
__device__ __forceinline__ float tanh_fast(float x) { return 2.f / (1.f + __expf(-2.f * x)) - 1.f; }

// Persistent GRU scan, PLAIN launch (no cooperative): sync is a custom flag
// protocol, so co-residency is the only requirement. __launch_bounds__(256,2)
// caps VGPRs at 256 -> >=2 blocks/CU capacity -> all 256 blocks resident even
// if some CUs are reserved. Each WG owns j-slice [jg*8, jg*8+8) of h for
// batches [g*4, g*4+4). Weights live entirely in VGPRs. h_t is stored at
// out[b][t][:] (generation-unique addresses -> no WAR hazards); cross-WG
// visibility via agent-scope (sc1) atomics only on h+flags, keeping x and
// weights cached in per-XCD L2 (no L2-wide invalidates).
__global__ __launch_bounds__(NTHR, 2)
void gru_fused(const float* __restrict__ x,
               const float* __restrict__ W_ih,
               const float* __restrict__ W_hh,
               const float* __restrict__ b_ih,
               const float* __restrict__ b_hh,
               float* __restrict__ out,
               unsigned* __restrict__ flags)
{
    const int tid  = threadIdx.x;
    const int sub  = tid & 31;        // k-lane (32-way split of K=512)
    const int slot = tid >> 5;        // j-offset within slice (0..7)
    const int wg   = blockIdx.x;
    const int jg   = wg & (NJ - 1);   // j-group 0..63
    const int g    = wg >> 6;         // batch-group 0..3
    const int jrow = jg * S + slot;   // my output h index
    const int b0   = g * BW;

    // ---- preload weights + biases into registers ----
    float4 wih[3][4], whh[3][4];
    float bi[3], bh[3];
#pragma unroll
    for (int gate = 0; gate < 3; ++gate) {
        const float* wi = W_ih + (size_t)(gate * HDIM + jrow) * HDIM;
        const float* wh = W_hh + (size_t)(gate * HDIM + jrow) * HDIM;
#pragma unroll
        for (int i = 0; i < 4; ++i) {
            const int c = (sub + 32 * i) * 4;
            wih[gate][i] = *(const float4*)(wi + c);
            whh[gate][i] = *(const float4*)(wh + c);
        }
        bi[gate] = b_ih[gate * HDIM + jrow];
        bh[gate] = b_hh[gate * HDIM + jrow];
    }

    unsigned* myflags = flags + g * NJ;

    for (int t = 0; t < TSTEPS; ++t) {
        // ============ GI phase: gi = W_ih_slice @ x_t (h-independent; hides sync) ============
        float4 vec[BW][4];
#pragma unroll
        for (int bb = 0; bb < BW; ++bb) {
            const float* xb = x + ((size_t)(b0 + bb) * TSTEPS + t) * HDIM;
#pragma unroll
            for (int i = 0; i < 4; ++i)
                vec[bb][i] = *(const float4*)(xb + (sub + 32 * i) * 4);
        }

        float acc[3][BW];
#pragma unroll
        for (int gate = 0; gate < 3; ++gate)
#pragma unroll
            for (int bb = 0; bb < BW; ++bb) acc[gate][bb] = 0.f;

#pragma unroll
        for (int i = 0; i < 4; ++i)
#pragma unroll
            for (int gate = 0; gate < 3; ++gate) {
                const float4 w = wih[gate][i];
#pragma unroll
                for (int bb = 0; bb < BW; ++bb) {
                    const float4 v = vec[bb][i];
                    float a = acc[gate][bb];
                    a = fmaf(w.x, v.x, a); a = fmaf(w.y, v.y, a);
                    a = fmaf(w.z, v.z, a); a = fmaf(w.w, v.w, a);
                    acc[gate][bb] = a;
                }
            }

        float gi[3][BW];
#pragma unroll
        for (int gate = 0; gate < 3; ++gate)
#pragma unroll
            for (int bb = 0; bb < BW; ++bb) {
                float v = acc[gate][bb];
                v += __shfl_xor(v, 16); v += __shfl_xor(v, 8);
                v += __shfl_xor(v, 4);  v += __shfl_xor(v, 2);
                v += __shfl_xor(v, 1);
                gi[gate][bb] = v + bi[gate];
            }

        // ============ wait for h_{t-1}, then GH phase ============
        float gh[3][BW];
        float hj[BW];
        if (t > 0) {
            if (tid < 64) {
                // one coalesced poll over all 64 domain flags; per-lane spin
                while (__hip_atomic_load(&myflags[tid], __ATOMIC_RELAXED,
                                         __HIP_MEMORY_SCOPE_AGENT) < (unsigned)t) { }
            }
            __syncthreads();
            asm volatile("" ::: "memory");   // no hoisting of h loads above the wait

#pragma unroll
            for (int bb = 0; bb < BW; ++bb) {
                const float* hb = out + ((size_t)(b0 + bb) * TSTEPS + (t - 1)) * HDIM;
#pragma unroll
                for (int i = 0; i < 4; ++i) {
                    const int c = (sub + 32 * i) * 4;
                    const u64 lo = __hip_atomic_load((const u64*)(hb + c),
                                                     __ATOMIC_RELAXED, __HIP_MEMORY_SCOPE_AGENT);
                    const u64 hi = __hip_atomic_load((const u64*)(hb + c + 2),
                                                     __ATOMIC_RELAXED, __HIP_MEMORY_SCOPE_AGENT);
                    vec[bb][i].x = __uint_as_float((unsigned)lo);
                    vec[bb][i].y = __uint_as_float((unsigned)(lo >> 32));
                    vec[bb][i].z = __uint_as_float((unsigned)hi);
                    vec[bb][i].w = __uint_as_float((unsigned)(hi >> 32));
                }
                hj[bb] = __hip_atomic_load(hb + jrow, __ATOMIC_RELAXED,
                                           __HIP_MEMORY_SCOPE_AGENT);
            }

#pragma unroll
            for (int gate = 0; gate < 3; ++gate)
#pragma unroll
                for (int bb = 0; bb < BW; ++bb) acc[gate][bb] = 0.f;

#pragma unroll
            for (int i = 0; i < 4; ++i)
#pragma unroll
                for (int gate = 0; gate < 3; ++gate) {
                    const float4 w = whh[gate][i];
#pragma unroll
                    for (int bb = 0; bb < BW; ++bb) {
                        const float4 v = vec[bb][i];
                        float a = acc[gate][bb];
                        a = fmaf(w.x, v.x, a); a = fmaf(w.y, v.y, a);
                        a = fmaf(w.z, v.z, a); a = fmaf(w.w, v.w, a);
                        acc[gate][bb] = a;
                    }
                }

#pragma unroll
            for (int gate = 0; gate < 3; ++gate)
#pragma unroll
                for (int bb = 0; bb < BW; ++bb) {
                    float v = acc[gate][bb];
                    v += __shfl_xor(v, 16); v += __shfl_xor(v, 8);
                    v += __shfl_xor(v, 4);  v += __shfl_xor(v, 2);
                    v += __shfl_xor(v, 1);
                    gh[gate][bb] = v + bh[gate];
                }
        } else {
#pragma unroll
            for (int bb = 0; bb < BW; ++bb) {
                hj[bb] = 0.f;
#pragma unroll
                for (int gate = 0; gate < 3; ++gate) gh[gate][bb] = bh[gate];
            }
        }

        // ============ combine + store h_t ============
#pragma unroll
        for (int bb = 0; bb < BW; ++bb) {
            const float r  = sigm(gi[0][bb] + gh[0][bb]);
            const float z  = sigm(gi[1][bb] + gh[1][bb]);
            const float n  = tanh_fast(gi[2][bb] + r * gh[2][bb]);
            const float hn = n + z * (hj[bb] - n);   // (1-z)n + z h
            if (sub == 0)
                __hip_atomic_store(out + ((size_t)(b0 + bb) * TSTEPS + t) * HDIM + jrow,
                                   hn, __ATOMIC_RELAXED, __HIP_MEMORY_SCOPE_AGENT);
        }

        __syncthreads();   // all waves' h' stores drained (vmcnt(0) before s_barrier)
        asm volatile("" ::: "memory");
        if (tid == 0)
            __hip_atomic_store(&myflags[jg], (unsigned)(t + 1),
                               __ATOMIC_RELEASE, __HIP_MEMORY_SCOPE_AGENT);
    }
}

extern "C" void kernel_launch(void* const* d_in, const int* in_sizes, int n_in,
                              void* d_out, int out_size, void* d_ws, size_t ws_size,
                              hipStream_t stream) {
    (void)in_sizes; (void)n_in; (void)out_size; (void)ws_size;
    const float* x   = (const float*)d_in[0];
    const float* Wih = (const float*)d_in[1];
    const float* Whh = (const float*)d_in[2];
    const float* bih = (const float*)d_in[3];
    const float* bhh = (const float*)d_in[4];
    float*       out = (float*)d_out;
    unsigned*  flags = (unsigned*)d_ws;

    // flags MUST start at 0 (ws is re-poisoned to 0xAA before every timed call;
    // poison would make every wait fall through -> race)
    hipMemsetAsync(d_ws, 0, NWG * sizeof(unsigned), stream);

    gru_fused<<<dim3(NWG), dim3(NTHR), 0, stream>>>(x, Wih, Whh, bih, bhh, out, flags);
}